// Round 16
// baseline (195.479 us; speedup 1.0000x reference)
//
#include <hip/hip_runtime.h>
#include <math.h>

#define F_IN 128
#define HIDN 128
#define EMBD 64
#define OUTC 40

#define NBINS 1024
#define BIN_SHIFT 7
#define CSR_BLKS 256

__host__ __device__ static inline int imin(int a, int b) { return a < b ? a : b; }

typedef __attribute__((ext_vector_type(8))) short s16x8;
typedef __attribute__((ext_vector_type(4))) float f32x4;

__device__ __forceinline__ unsigned short f2bf(float f) {
    unsigned int u = __builtin_bit_cast(unsigned int, f);
    u = (u + 0x7FFFu + ((u >> 16) & 1u)) >> 16;
    return (unsigned short)u;
}
__device__ __forceinline__ float bflo(unsigned int v) {
    return __builtin_bit_cast(float, v << 16);
}
__device__ __forceinline__ float bfhi(unsigned int v) {
    return __builtin_bit_cast(float, v & 0xFFFF0000u);
}

__host__ __device__ static inline int csr_chunk(int E) {
    return (((E + CSR_BLKS - 1) / CSR_BLKS) + 3) & ~3;
}

// ========= weight fragment precompute (bf16, exact per-lane MFMA layout) =========
__global__ __launch_bounds__(256) void prep_frags_kernel(
    const float* __restrict__ W1, const float* __restrict__ W2,
    const float* __restrict__ Wl, unsigned short* __restrict__ W1f,
    unsigned short* __restrict__ W2f, unsigned short* __restrict__ Wlf) {
    int s = blockIdx.x * 256 + threadIdx.x;
    if (s < 2048) {
        int lane = s & 63, r = s >> 6;
        int ks = r & 3, cf = (r >> 2) & 3, wcol = r >> 4;
        int c = wcol * 64 + cf * 16 + (lane & 15);
        int kb = ks * 32 + (lane >> 4) * 8;
        unsigned short* d = W1f + s * 8;
#pragma unroll
        for (int j = 0; j < 8; ++j) d[j] = f2bf(W1[(size_t)(kb + j) * HIDN + c]);
    } else if (s < 3072) {
        int q = s - 2048;
        int lane = q & 63, r = q >> 6;
        int ks = r & 3, wv = r >> 2;
        int c = wv * 16 + (lane & 15);
        int kb = ks * 32 + (lane >> 4) * 8;
        unsigned short* d = W2f + q * 8;
#pragma unroll
        for (int j = 0; j < 8; ++j) d[j] = f2bf(W2[(size_t)(kb + j) * EMBD + c]);
    } else if (s < 3456) {
        int q = s - 3072;
        int lane = q & 63, r = q >> 6;
        int ks = r & 1, ct = r >> 1;
        int c = ct * 16 + (lane & 15);
        int kb = ks * 32 + (lane >> 4) * 8;
        unsigned short* d = Wlf + q * 8;
#pragma unroll
        for (int j = 0; j < 8; ++j)
            d[j] = (c < OUTC) ? f2bf(Wl[(size_t)(kb + j) * OUTC + c]) : (unsigned short)0;
    }
}

// ================= CSR build via two-level counting sort (LDS atomics only) =================
__global__ __launch_bounds__(256) void coarse_hist_kernel(const int* __restrict__ dst,
                                                          int* __restrict__ bc, int E) {
    __shared__ int h[NBINS];
    for (int i = threadIdx.x; i < NBINS; i += 256) h[i] = 0;
    __syncthreads();
    const int chunk = csr_chunk(E);
    const int e0 = blockIdx.x * chunk;
    const int e1 = imin(e0 + chunk, E);
    int e = e0 + threadIdx.x * 4;
    for (; e + 3 < e1; e += 256 * 4) {
        int4 d = *(const int4*)(dst + e);
        atomicAdd(&h[d.x >> BIN_SHIFT], 1);
        atomicAdd(&h[d.y >> BIN_SHIFT], 1);
        atomicAdd(&h[d.z >> BIN_SHIFT], 1);
        atomicAdd(&h[d.w >> BIN_SHIFT], 1);
    }
    for (; e < e1; ++e) atomicAdd(&h[dst[e] >> BIN_SHIFT], 1);
    __syncthreads();
    for (int i = threadIdx.x; i < NBINS; i += 256)
        bc[blockIdx.x * NBINS + i] = h[i];
}

__global__ __launch_bounds__(64) void bin_prefix_kernel(int* __restrict__ bc,
                                                        int* __restrict__ bintot) {
    const int bin = blockIdx.x * 64 + threadIdx.x;
    int run = 0;
    for (int blk = 0; blk < CSR_BLKS; ++blk) {
        int v = bc[blk * NBINS + bin];
        bc[blk * NBINS + bin] = run;
        run += v;
    }
    bintot[bin] = run;
}

__global__ __launch_bounds__(1024) void bin_scan_kernel(const int* __restrict__ bintot,
                                                        int* __restrict__ cs) {
    __shared__ int s[NBINS];
    const int t = threadIdx.x;
    s[t] = bintot[t];
    __syncthreads();
    for (int off = 1; off < NBINS; off <<= 1) {
        int v = (t >= off) ? s[t - off] : 0;
        __syncthreads();
        s[t] += v;
        __syncthreads();
    }
    cs[t + 1] = s[t];
    if (t == 0) cs[0] = 0;
}

__global__ __launch_bounds__(256) void bin_scatter_kernel(const int* __restrict__ src,
                                                          const int* __restrict__ dst,
                                                          const int* __restrict__ bc,
                                                          const int* __restrict__ cs,
                                                          int* __restrict__ ebuf, int E) {
    __shared__ int cur[NBINS];
    for (int i = threadIdx.x; i < NBINS; i += 256)
        cur[i] = cs[i] + bc[blockIdx.x * NBINS + i];
    __syncthreads();
    const int chunk = csr_chunk(E);
    const int e0 = blockIdx.x * chunk;
    const int e1 = imin(e0 + chunk, E);
    int e = e0 + threadIdx.x * 4;
    for (; e + 3 < e1; e += 256 * 4) {
        int4 d = *(const int4*)(dst + e);
        int4 s = *(const int4*)(src + e);
        int p0 = atomicAdd(&cur[d.x >> BIN_SHIFT], 1);
        int p1 = atomicAdd(&cur[d.y >> BIN_SHIFT], 1);
        int p2 = atomicAdd(&cur[d.z >> BIN_SHIFT], 1);
        int p3 = atomicAdd(&cur[d.w >> BIN_SHIFT], 1);
        ebuf[p0] = (s.x << BIN_SHIFT) | (d.x & 127);
        ebuf[p1] = (s.y << BIN_SHIFT) | (d.y & 127);
        ebuf[p2] = (s.z << BIN_SHIFT) | (d.z & 127);
        ebuf[p3] = (s.w << BIN_SHIFT) | (d.w & 127);
    }
    for (; e < e1; ++e) {
        int d = dst[e];
        int pos = atomicAdd(&cur[d >> BIN_SHIFT], 1);
        ebuf[pos] = (src[e] << BIN_SHIFT) | (d & 127);
    }
}

// Pass D: fine histogram + scan -> degi/rowptr/dinv + col, PLUS per-bin degree-rank
// permutation perm[node0+rank]=node (counting sort by degree) for load-balanced gathers.
__global__ __launch_bounds__(256) void fine_build_kernel(const int* __restrict__ ebuf,
                                                         const int* __restrict__ cs,
                                                         int* __restrict__ degi,
                                                         int* __restrict__ rowptr,
                                                         float* __restrict__ dinv,
                                                         int* __restrict__ col,
                                                         int* __restrict__ perm, int n) {
    __shared__ int h[128];
    __shared__ int fs[128];
    __shared__ int cur[128];
    const int b = blockIdx.x;
    const int node0 = b << BIN_SHIFT;
    const int t = threadIdx.x;
    if (t < 128) h[t] = 0;
    __syncthreads();
    const int e0 = cs[b], e1 = cs[b + 1];
    for (int e = e0 + t; e < e1; e += 256)
        atomicAdd(&h[ebuf[e] & 127], 1);
    __syncthreads();
    if (t < 128) fs[t] = h[t];
    __syncthreads();
    for (int off = 1; off < 128; off <<= 1) {
        int v = 0;
        if (t < 128 && t >= off) v = fs[t - off];
        __syncthreads();
        if (t < 128) fs[t] += v;  // inclusive scan
        __syncthreads();
    }
    if (t < 128) {
        int node = node0 + t;
        if (node < n) {
            int cnt = h[t];
            degi[node] = cnt;
            rowptr[node] = e0 + fs[t] - cnt;
            dinv[node] = rsqrtf((float)cnt + 1.0f);
        }
        cur[t] = 0;
    }
    __syncthreads();
    for (int e = e0 + t; e < e1; e += 256) {
        int p = ebuf[e];
        int li = p & 127;
        int loc = atomicAdd(&cur[li], 1);
        col[e0 + (fs[li] - h[li]) + loc] = p >> BIN_SHIFT;
    }
    // ---- degree-rank permutation (counting sort over clamped degree) ----
    __syncthreads();
    if (t < 128) cur[t] = 0;
    __syncthreads();
    int mydeg = 0;
    const bool valid = (t < 128) && (node0 + t < n);
    if (valid) {
        mydeg = imin(h[t], 127);
        atomicAdd(&cur[mydeg], 1);
    }
    __syncthreads();
    if (t < 128) fs[t] = cur[t];
    __syncthreads();
    for (int off = 1; off < 128; off <<= 1) {
        int v = 0;
        if (t < 128 && t >= off) v = fs[t - off];
        __syncthreads();
        if (t < 128) fs[t] += v;
        __syncthreads();
    }
    if (t < 128) cur[t] = fs[t] - cur[t];  // exclusive base -> cursor
    __syncthreads();
    if (valid) {
        int r = atomicAdd(&cur[mydeg], 1);
        perm[node0 + r] = node0 + t;
    }
}

// ---------------- MFMA bf16 GEMM (layer1): Y(bf16) = dinv[row] * (X @ W) ----------------
template <typename InT, int K, int M, int WM, int WN>
__global__ __launch_bounds__(256) void gemm_mfma_kernel(const InT* __restrict__ X,
                                                        const unsigned short* __restrict__ Wfrag,
                                                        const float* __restrict__ dinv,
                                                        unsigned short* __restrict__ Y,
                                                        int n, int ntiles) {
    constexpr int BM = 64;
    constexpr int WR = BM / WM;
    constexpr int WC = M / WN;
    constexpr int RF = WR / 16;
    constexpr int CF = WC / 16;
    constexpr int KS = K / 32;
    constexpr int ROWB = K * 2;
    constexpr int UPR = ROWB / 16;

    __shared__ char Xs[BM * ROWB];

    const int tid = threadIdx.x;
    const int lane = tid & 63;
    const int wid = tid >> 6;
    const int wrow = wid / WN;
    const int wcol = wid % WN;
    const int l15 = lane & 15;
    const int lhi = lane >> 4;

    s16x8 bfrag[CF][KS];
#pragma unroll
    for (int cf = 0; cf < CF; ++cf)
#pragma unroll
        for (int ks = 0; ks < KS; ++ks)
            bfrag[cf][ks] = *(const s16x8*)(Wfrag +
                (size_t)(((wcol * CF + cf) * KS + ks) * 64 + lane) * 8);

    for (int tile = blockIdx.x; tile < ntiles; tile += gridDim.x) {
        const int row0 = tile * BM;
        __syncthreads();
#pragma unroll
        for (int i = 0; i < (BM * UPR) / 256; ++i) {
            int g = i * 256 + tid;
            int r = g / UPR, u = g % UPR;
            int grow = row0 + r;
            int4 val = make_int4(0, 0, 0, 0);
            if (grow < n) {
                if constexpr (sizeof(InT) == 4) {
                    const float* src = (const float*)X + (size_t)grow * K + u * 8;
                    float4 f0 = *(const float4*)src;
                    float4 f1 = *(const float4*)(src + 4);
                    val.x = (int)(f2bf(f0.x) | ((unsigned int)f2bf(f0.y) << 16));
                    val.y = (int)(f2bf(f0.z) | ((unsigned int)f2bf(f0.w) << 16));
                    val.z = (int)(f2bf(f1.x) | ((unsigned int)f2bf(f1.y) << 16));
                    val.w = (int)(f2bf(f1.z) | ((unsigned int)f2bf(f1.w) << 16));
                } else {
                    val = *(const int4*)((const unsigned short*)X + (size_t)grow * K + u * 8);
                }
            }
            *(int4*)(Xs + r * ROWB + ((u ^ (r & 7)) * 16)) = val;
        }
        __syncthreads();

        f32x4 acc[RF][CF];
#pragma unroll
        for (int rf = 0; rf < RF; ++rf)
#pragma unroll
            for (int cf = 0; cf < CF; ++cf) acc[rf][cf] = (f32x4)(0.0f);
#pragma unroll
        for (int ks = 0; ks < KS; ++ks) {
            s16x8 afrag[RF];
#pragma unroll
            for (int rf = 0; rf < RF; ++rf) {
                int r = wrow * WR + rf * 16 + l15;
                int u = ks * 4 + lhi;
                afrag[rf] = *(const s16x8*)(Xs + r * ROWB + ((u ^ (r & 7)) * 16));
            }
#pragma unroll
            for (int rf = 0; rf < RF; ++rf)
#pragma unroll
                for (int cf = 0; cf < CF; ++cf)
                    acc[rf][cf] = __builtin_amdgcn_mfma_f32_16x16x32_bf16(
                        afrag[rf], bfrag[cf][ks], acc[rf][cf], 0, 0, 0);
        }

#pragma unroll
        for (int rf = 0; rf < RF; ++rf) {
#pragma unroll
            for (int reg = 0; reg < 4; ++reg) {
                int grow = row0 + wrow * WR + rf * 16 + lhi * 4 + reg;
                if (grow < n) {
                    float dv = dinv[grow];
#pragma unroll
                    for (int cf = 0; cf < CF; ++cf) {
                        int colg = wcol * WC + cf * 16 + l15;
                        Y[(size_t)grow * M + colg] = f2bf(acc[rf][cf][reg] * dv);
                    }
                }
            }
        }
    }
}

// ======== FUSED: h=relu(dinv*agg(Hs1)+b1) -> LDS bf16 tile -> Hs2=bf16(dinv*(h@W2)) ========
// Nodes taken via degree-rank perm (bin-aligned) so each block's 16 nodes balance.
__global__ __launch_bounds__(256) void gather_gemm_kernel(
    const unsigned short* __restrict__ Hs1, const int* __restrict__ rowptr,
    const int* __restrict__ degi, const int* __restrict__ col,
    const float* __restrict__ dinv, const float* __restrict__ b1,
    const unsigned short* __restrict__ W2f, const int* __restrict__ perm,
    unsigned short* __restrict__ Hs2, int n) {
    __shared__ char h_tile[16 * 256];
    __shared__ int nodes[16];

    const int tid = threadIdx.x;
    const int lane = tid & 63;
    const int wv = tid >> 6;
    const int sub = lane & 15;
    const int grp = lane >> 4;
    const int node0 = blockIdx.x * 16;
    const int local = wv * 4 + grp;
    const int idx = node0 + local;
    const int node = (idx < n) ? perm[idx] : -1;
    if (tid < 16) nodes[tid] = (node0 + tid < n) ? perm[node0 + tid] : -1;
    const int foff = sub * 8;

    s16x8 bfrag[4];
#pragma unroll
    for (int ks = 0; ks < 4; ++ks)
        bfrag[ks] = *(const s16x8*)(W2f + (size_t)((wv * 4 + ks) * 64 + lane) * 8);

    if (node >= 0) {
        const int start = rowptr[node];
        const int cnt = degi[node];
        const float dvn = dinv[node];
        float acc[8];
        {
            int4 v = *(const int4*)(Hs1 + (size_t)node * HIDN + foff);
#pragma unroll
            for (int q = 0; q < 4; ++q) {
                unsigned int w = ((const unsigned int*)&v)[q];
                acc[2 * q] = bflo(w);
                acc[2 * q + 1] = bfhi(w);
            }
        }
        int m0 = imin(cnt, 16);
        int sv = (sub < m0) ? col[start + sub] : 0;
        for (int base = 0; base < cnt; base += 16) {
            int m = imin(cnt - base, 16);
            int svn = 0;
            int nb = base + 16;
            if (nb < cnt) {
                int mn = imin(cnt - nb, 16);
                svn = (sub < mn) ? col[start + nb + sub] : 0;
            }
            int k = 0;
            for (; k + 8 <= m; k += 8) {
                int4 a[8];
#pragma unroll
                for (int j = 0; j < 8; ++j) {
                    int s = __shfl(sv, k + j, 16);
                    a[j] = *(const int4*)(Hs1 + (size_t)s * HIDN + foff);
                }
#pragma unroll
                for (int j = 0; j < 8; ++j)
#pragma unroll
                    for (int q = 0; q < 4; ++q) {
                        unsigned int w = ((const unsigned int*)&a[j])[q];
                        acc[2 * q] += bflo(w);
                        acc[2 * q + 1] += bfhi(w);
                    }
            }
            for (; k + 2 <= m; k += 2) {
                int s0 = __shfl(sv, k, 16);
                int s1 = __shfl(sv, k + 1, 16);
                int4 a0 = *(const int4*)(Hs1 + (size_t)s0 * HIDN + foff);
                int4 a1 = *(const int4*)(Hs1 + (size_t)s1 * HIDN + foff);
#pragma unroll
                for (int q = 0; q < 4; ++q) {
                    unsigned int w0 = ((const unsigned int*)&a0)[q];
                    unsigned int w1 = ((const unsigned int*)&a1)[q];
                    acc[2 * q] += bflo(w0);
                    acc[2 * q + 1] += bfhi(w0);
                    acc[2 * q] += bflo(w1);
                    acc[2 * q + 1] += bfhi(w1);
                }
            }
            for (; k < m; ++k) {
                int s = __shfl(sv, k, 16);
                int4 a = *(const int4*)(Hs1 + (size_t)s * HIDN + foff);
#pragma unroll
                for (int q = 0; q < 4; ++q) {
                    unsigned int w = ((const unsigned int*)&a)[q];
                    acc[2 * q] += bflo(w);
                    acc[2 * q + 1] += bfhi(w);
                }
            }
            sv = svn;
        }
        float4 bv0 = *(const float4*)(b1 + foff);
        float4 bv1 = *(const float4*)(b1 + foff + 4);
        float o[8];
        o[0] = fmaxf(dvn * acc[0] + bv0.x, 0.f);
        o[1] = fmaxf(dvn * acc[1] + bv0.y, 0.f);
        o[2] = fmaxf(dvn * acc[2] + bv0.z, 0.f);
        o[3] = fmaxf(dvn * acc[3] + bv0.w, 0.f);
        o[4] = fmaxf(dvn * acc[4] + bv1.x, 0.f);
        o[5] = fmaxf(dvn * acc[5] + bv1.y, 0.f);
        o[6] = fmaxf(dvn * acc[6] + bv1.z, 0.f);
        o[7] = fmaxf(dvn * acc[7] + bv1.w, 0.f);
        int4 p;
        ((unsigned int*)&p)[0] = f2bf(o[0]) | ((unsigned int)f2bf(o[1]) << 16);
        ((unsigned int*)&p)[1] = f2bf(o[2]) | ((unsigned int)f2bf(o[3]) << 16);
        ((unsigned int*)&p)[2] = f2bf(o[4]) | ((unsigned int)f2bf(o[5]) << 16);
        ((unsigned int*)&p)[3] = f2bf(o[6]) | ((unsigned int)f2bf(o[7]) << 16);
        *(int4*)(h_tile + local * 256 + ((sub ^ (local & 7)) * 16)) = p;
    }
    __syncthreads();

    f32x4 acc2 = (f32x4)(0.0f);
#pragma unroll
    for (int ks = 0; ks < 4; ++ks) {
        int r = sub;
        int u = ks * 4 + grp;
        s16x8 af = *(const s16x8*)(h_tile + r * 256 + ((u ^ (r & 7)) * 16));
        acc2 = __builtin_amdgcn_mfma_f32_16x16x32_bf16(af, bfrag[ks], acc2, 0, 0, 0);
    }
#pragma unroll
    for (int reg = 0; reg < 4; ++reg) {
        int row = grp * 4 + reg;
        int nd = nodes[row];
        if (nd >= 0)
            Hs2[(size_t)nd * EMBD + wv * 16 + sub] = f2bf(acc2[reg] * dinv[nd]);
    }
}

// ======== FUSED final: emb = dinv*agg(Hs2)+b2 (f32) ; MFMA logits ; log_softmax ========
__global__ __launch_bounds__(256) void gather2_lsm_kernel(
    const unsigned short* __restrict__ Hs, const int* __restrict__ rowptr,
    const int* __restrict__ degi, const int* __restrict__ col,
    const float* __restrict__ dinv, const float* __restrict__ b2,
    const unsigned short* __restrict__ Wlf, const float* __restrict__ bl,
    const int* __restrict__ perm, float* __restrict__ emb,
    float* __restrict__ lsm, int n) {
    __shared__ char h_tile[32 * 128];
    __shared__ float lg[32][49];
    __shared__ float bls[OUTC];

    const int tid = threadIdx.x;
    if (tid < OUTC) bls[tid] = bl[tid];
    const int lane = tid & 63;
    const int wv = tid >> 6;
    const int sub = lane & 7;
    const int grp = lane >> 3;
    const int local = wv * 8 + grp;
    const int node0 = blockIdx.x * 32;
    const int idx = node0 + local;
    const int node = (idx < n) ? perm[idx] : -1;
    const int foff = sub * 8;

    if (node >= 0) {
        const int start = rowptr[node];
        const int cnt = degi[node];
        const float dvn = dinv[node];
        float acc[8];
        {
            int4 v = *(const int4*)(Hs + (size_t)node * EMBD + foff);
#pragma unroll
            for (int q = 0; q < 4; ++q) {
                unsigned int w = ((const unsigned int*)&v)[q];
                acc[2 * q] = bflo(w);
                acc[2 * q + 1] = bfhi(w);
            }
        }
        int m0 = imin(cnt, 8);
        int sv = (sub < m0) ? col[start + sub] : 0;
        for (int base = 0; base < cnt; base += 8) {
            int m = imin(cnt - base, 8);
            int svn = 0;
            int nb = base + 8;
            if (nb < cnt) {
                int mn = imin(cnt - nb, 8);
                svn = (sub < mn) ? col[start + nb + sub] : 0;
            }
            int k = 0;
            for (; k + 8 <= m; k += 8) {
                int4 a[8];
#pragma unroll
                for (int j = 0; j < 8; ++j) {
                    int s = __shfl(sv, k + j, 8);
                    a[j] = *(const int4*)(Hs + (size_t)s * EMBD + foff);
                }
#pragma unroll
                for (int j = 0; j < 8; ++j)
#pragma unroll
                    for (int q = 0; q < 4; ++q) {
                        unsigned int w = ((const unsigned int*)&a[j])[q];
                        acc[2 * q] += bflo(w);
                        acc[2 * q + 1] += bfhi(w);
                    }
            }
            for (; k < m; ++k) {
                int s = __shfl(sv, k, 8);
                int4 a = *(const int4*)(Hs + (size_t)s * EMBD + foff);
#pragma unroll
                for (int q = 0; q < 4; ++q) {
                    unsigned int w = ((const unsigned int*)&a)[q];
                    acc[2 * q] += bflo(w);
                    acc[2 * q + 1] += bfhi(w);
                }
            }
            sv = svn;
        }

        float4 bv0 = *(const float4*)(b2 + foff);
        float4 bv1 = *(const float4*)(b2 + foff + 4);
        float o[8];
        o[0] = dvn * acc[0] + bv0.x; o[1] = dvn * acc[1] + bv0.y;
        o[2] = dvn * acc[2] + bv0.z; o[3] = dvn * acc[3] + bv0.w;
        o[4] = dvn * acc[4] + bv1.x; o[5] = dvn * acc[5] + bv1.y;
        o[6] = dvn * acc[6] + bv1.z; o[7] = dvn * acc[7] + bv1.w;
        *(float4*)(emb + (size_t)node * EMBD + foff) = make_float4(o[0], o[1], o[2], o[3]);
        *(float4*)(emb + (size_t)node * EMBD + foff + 4) = make_float4(o[4], o[5], o[6], o[7]);
        int4 p;
        ((unsigned int*)&p)[0] = f2bf(o[0]) | ((unsigned int)f2bf(o[1]) << 16);
        ((unsigned int*)&p)[1] = f2bf(o[2]) | ((unsigned int)f2bf(o[3]) << 16);
        ((unsigned int*)&p)[2] = f2bf(o[4]) | ((unsigned int)f2bf(o[5]) << 16);
        ((unsigned int*)&p)[3] = f2bf(o[6]) | ((unsigned int)f2bf(o[7]) << 16);
        *(int4*)(h_tile + local * 128 + ((sub ^ (local & 7)) * 16)) = p;
    }
    __syncthreads();

    const int l15 = lane & 15;
    const int lhi = lane >> 4;
#pragma unroll
    for (int it = 0; it < 2; ++it) {
        int t = wv + it * 4;
        if (t < 6) {
            int rt = t & 1, ct = t >> 1;
            f32x4 accl = (f32x4)(0.0f);
#pragma unroll
            for (int ks = 0; ks < 2; ++ks) {
                int r = rt * 16 + l15;
                int u = ks * 4 + lhi;
                s16x8 af = *(const s16x8*)(h_tile + r * 128 + ((u ^ (r & 7)) * 16));
                s16x8 bf = *(const s16x8*)(Wlf + (size_t)((ct * 2 + ks) * 64 + lane) * 8);
                accl = __builtin_amdgcn_mfma_f32_16x16x32_bf16(af, bf, accl, 0, 0, 0);
            }
#pragma unroll
            for (int reg = 0; reg < 4; ++reg)
                lg[rt * 16 + lhi * 4 + reg][ct * 16 + l15] = accl[reg];
        }
    }
    __syncthreads();

    if (tid < 32) {
        int idx2 = node0 + tid;
        if (idx2 < n) {
            int nd = perm[idx2];
            float logit[OUTC];
            float mx = -INFINITY;
#pragma unroll
            for (int c = 0; c < OUTC; ++c) {
                float v = lg[tid][c] + bls[c];
                logit[c] = v;
                mx = fmaxf(mx, v);
            }
            float ss = 0.0f;
#pragma unroll
            for (int c = 0; c < OUTC; ++c) ss += expf(logit[c] - mx);
            float lse = mx + logf(ss);
            float* op = lsm + (size_t)nd * OUTC;
#pragma unroll
            for (int c = 0; c < OUTC; ++c) op[c] = logit[c] - lse;
        }
    }
}

extern "C" void kernel_launch(void* const* d_in, const int* in_sizes, int n_in,
                              void* d_out, int out_size, void* d_ws, size_t ws_size,
                              hipStream_t stream) {
    const float* x  = (const float*)d_in[0];
    const int*   ei = (const int*)d_in[1];
    const float* W1 = (const float*)d_in[2];
    const float* b1 = (const float*)d_in[3];
    const float* W2 = (const float*)d_in[4];
    const float* b2 = (const float*)d_in[5];
    const float* Wl = (const float*)d_in[6];
    const float* bl = (const float*)d_in[7];

    const int N = in_sizes[0] / F_IN;
    const int E = in_sizes[1] / 2;
    const int* srcp = ei;
    const int* dstp = ei + E;

    float* out = (float*)d_out;
    float* lsm = out;                        // N x 40
    float* emb = out + (size_t)N * OUTC;     // N x 64

    float* ws    = (float*)d_ws;
    float* dinv  = ws;                              // N
    int*   degi  = (int*)(ws + N);                  // N
    int*   rowptr= degi + N;                        // N
    int*   perm  = rowptr + N;                      // N + 128
    int*   cs    = perm + N + 128;                  // NBINS+1 (pad 1056)
    int*   bintot= cs + 1056;                       // NBINS
    int*   bc    = bintot + NBINS;                  // CSR_BLKS*NBINS (block-major)
    unsigned short* W1f = (unsigned short*)(bc + CSR_BLKS * NBINS);  // 16384
    unsigned short* W2f = W1f + 16384;                               // 8192
    unsigned short* Wlf = W2f + 8192;                                // 3072
    int*   col   = (int*)(Wlf + 3072);              // E
    int*   ebuf  = col + E;                         // E (packed (src<<7)|dst7)
    unsigned short* Hs1 = (unsigned short*)(ebuf + E);     // N x 128 bf16
    unsigned short* Hs2 = Hs1 + (size_t)N * HIDN;          // N x 64 bf16

    const int B = 256;
    const int ntiles = (N + 63) / 64;

    // --- weight fragments (tiny, once) ---
    prep_frags_kernel<<<14, B, 0, stream>>>(W1, W2, Wl, W1f, W2f, Wlf);

    // --- CSR build (two-level counting sort, LDS atomics only) ---
    coarse_hist_kernel<<<CSR_BLKS, B, 0, stream>>>(dstp, bc, E);
    bin_prefix_kernel<<<NBINS / 64, 64, 0, stream>>>(bc, bintot);
    bin_scan_kernel<<<1, 1024, 0, stream>>>(bintot, cs);
    bin_scatter_kernel<<<CSR_BLKS, B, 0, stream>>>(srcp, dstp, bc, cs, ebuf, E);
    fine_build_kernel<<<(N + 127) / 128, B, 0, stream>>>(ebuf, cs, degi, rowptr, dinv,
                                                         col, perm, N);

    // --- layer 1 GEMM: Hs1 = bf16(dinv .* (x @ W1)) ---
    gemm_mfma_kernel<float, F_IN, HIDN, 2, 2><<<ntiles, B, 0, stream>>>(x, W1f, dinv, Hs1, N, ntiles);

    // --- fused: gather layer1 + ReLU + GEMM2 -> Hs2 (degree-balanced via perm) ---
    gather_gemm_kernel<<<(N + 15) / 16, B, 0, stream>>>(
        Hs1, rowptr, degi, col, dinv, b1, W2f, perm, Hs2, N);

    // --- fused: gather layer2 -> emb + MFMA logits + log_softmax (perm-balanced) ---
    gather2_lsm_kernel<<<(N + 31) / 32, B, 0, stream>>>(
        Hs2, rowptr, degi, col, dinv, b2, Wlf, bl, perm, emb, lsm, N);
}

// Round 17
// 184.482 us; speedup vs baseline: 1.0596x; 1.0596x over previous
//
#include <hip/hip_runtime.h>
#include <math.h>

#define F_IN 128
#define HIDN 128
#define EMBD 64
#define OUTC 40

#define NBINS 1024
#define BIN_SHIFT 7
#define CSR_BLKS 256

__host__ __device__ static inline int imin(int a, int b) { return a < b ? a : b; }

typedef __attribute__((ext_vector_type(8))) short s16x8;
typedef __attribute__((ext_vector_type(4))) float f32x4;

__device__ __forceinline__ unsigned short f2bf(float f) {
    unsigned int u = __builtin_bit_cast(unsigned int, f);
    u = (u + 0x7FFFu + ((u >> 16) & 1u)) >> 16;
    return (unsigned short)u;
}
__device__ __forceinline__ float bflo(unsigned int v) {
    return __builtin_bit_cast(float, v << 16);
}
__device__ __forceinline__ float bfhi(unsigned int v) {
    return __builtin_bit_cast(float, v & 0xFFFF0000u);
}

__host__ __device__ static inline int csr_chunk(int E) {
    return (((E + CSR_BLKS - 1) / CSR_BLKS) + 3) & ~3;
}

// ========= weight fragment precompute (bf16, exact per-lane MFMA layout) =========
__global__ __launch_bounds__(256) void prep_frags_kernel(
    const float* __restrict__ W1, const float* __restrict__ W2,
    const float* __restrict__ Wl, unsigned short* __restrict__ W1f,
    unsigned short* __restrict__ W2f, unsigned short* __restrict__ Wlf) {
    int s = blockIdx.x * 256 + threadIdx.x;
    if (s < 2048) {
        int lane = s & 63, r = s >> 6;
        int ks = r & 3, cf = (r >> 2) & 3, wcol = r >> 4;
        int c = wcol * 64 + cf * 16 + (lane & 15);
        int kb = ks * 32 + (lane >> 4) * 8;
        unsigned short* d = W1f + s * 8;
#pragma unroll
        for (int j = 0; j < 8; ++j) d[j] = f2bf(W1[(size_t)(kb + j) * HIDN + c]);
    } else if (s < 3072) {
        int q = s - 2048;
        int lane = q & 63, r = q >> 6;
        int ks = r & 3, wv = r >> 2;
        int c = wv * 16 + (lane & 15);
        int kb = ks * 32 + (lane >> 4) * 8;
        unsigned short* d = W2f + q * 8;
#pragma unroll
        for (int j = 0; j < 8; ++j) d[j] = f2bf(W2[(size_t)(kb + j) * EMBD + c]);
    } else if (s < 3456) {
        int q = s - 3072;
        int lane = q & 63, r = q >> 6;
        int ks = r & 1, ct = r >> 1;
        int c = ct * 16 + (lane & 15);
        int kb = ks * 32 + (lane >> 4) * 8;
        unsigned short* d = Wlf + q * 8;
#pragma unroll
        for (int j = 0; j < 8; ++j)
            d[j] = (c < OUTC) ? f2bf(Wl[(size_t)(kb + j) * OUTC + c]) : (unsigned short)0;
    }
}

// ================= CSR build via two-level counting sort (LDS atomics only) =================
__global__ __launch_bounds__(256) void coarse_hist_kernel(const int* __restrict__ dst,
                                                          int* __restrict__ bc, int E) {
    __shared__ int h[NBINS];
    for (int i = threadIdx.x; i < NBINS; i += 256) h[i] = 0;
    __syncthreads();
    const int chunk = csr_chunk(E);
    const int e0 = blockIdx.x * chunk;
    const int e1 = imin(e0 + chunk, E);
    int e = e0 + threadIdx.x * 4;
    for (; e + 3 < e1; e += 256 * 4) {
        int4 d = *(const int4*)(dst + e);
        atomicAdd(&h[d.x >> BIN_SHIFT], 1);
        atomicAdd(&h[d.y >> BIN_SHIFT], 1);
        atomicAdd(&h[d.z >> BIN_SHIFT], 1);
        atomicAdd(&h[d.w >> BIN_SHIFT], 1);
    }
    for (; e < e1; ++e) atomicAdd(&h[dst[e] >> BIN_SHIFT], 1);
    __syncthreads();
    for (int i = threadIdx.x; i < NBINS; i += 256)
        bc[blockIdx.x * NBINS + i] = h[i];
}

__global__ __launch_bounds__(64) void bin_prefix_kernel(int* __restrict__ bc,
                                                        int* __restrict__ bintot) {
    const int bin = blockIdx.x * 64 + threadIdx.x;
    int run = 0;
    for (int blk = 0; blk < CSR_BLKS; ++blk) {
        int v = bc[blk * NBINS + bin];
        bc[blk * NBINS + bin] = run;
        run += v;
    }
    bintot[bin] = run;
}

__global__ __launch_bounds__(1024) void bin_scan_kernel(const int* __restrict__ bintot,
                                                        int* __restrict__ cs) {
    __shared__ int s[NBINS];
    const int t = threadIdx.x;
    s[t] = bintot[t];
    __syncthreads();
    for (int off = 1; off < NBINS; off <<= 1) {
        int v = (t >= off) ? s[t - off] : 0;
        __syncthreads();
        s[t] += v;
        __syncthreads();
    }
    cs[t + 1] = s[t];
    if (t == 0) cs[0] = 0;
}

__global__ __launch_bounds__(256) void bin_scatter_kernel(const int* __restrict__ src,
                                                          const int* __restrict__ dst,
                                                          const int* __restrict__ bc,
                                                          const int* __restrict__ cs,
                                                          int* __restrict__ ebuf, int E) {
    __shared__ int cur[NBINS];
    for (int i = threadIdx.x; i < NBINS; i += 256)
        cur[i] = cs[i] + bc[blockIdx.x * NBINS + i];
    __syncthreads();
    const int chunk = csr_chunk(E);
    const int e0 = blockIdx.x * chunk;
    const int e1 = imin(e0 + chunk, E);
    int e = e0 + threadIdx.x * 4;
    for (; e + 3 < e1; e += 256 * 4) {
        int4 d = *(const int4*)(dst + e);
        int4 s = *(const int4*)(src + e);
        int p0 = atomicAdd(&cur[d.x >> BIN_SHIFT], 1);
        int p1 = atomicAdd(&cur[d.y >> BIN_SHIFT], 1);
        int p2 = atomicAdd(&cur[d.z >> BIN_SHIFT], 1);
        int p3 = atomicAdd(&cur[d.w >> BIN_SHIFT], 1);
        ebuf[p0] = (s.x << BIN_SHIFT) | (d.x & 127);
        ebuf[p1] = (s.y << BIN_SHIFT) | (d.y & 127);
        ebuf[p2] = (s.z << BIN_SHIFT) | (d.z & 127);
        ebuf[p3] = (s.w << BIN_SHIFT) | (d.w & 127);
    }
    for (; e < e1; ++e) {
        int d = dst[e];
        int pos = atomicAdd(&cur[d >> BIN_SHIFT], 1);
        ebuf[pos] = (src[e] << BIN_SHIFT) | (d & 127);
    }
}

__global__ __launch_bounds__(256) void fine_build_kernel(const int* __restrict__ ebuf,
                                                         const int* __restrict__ cs,
                                                         int* __restrict__ degi,
                                                         int* __restrict__ rowptr,
                                                         float* __restrict__ dinv,
                                                         int* __restrict__ col, int n) {
    __shared__ int h[128];
    __shared__ int fs[128];
    __shared__ int cur[128];
    const int b = blockIdx.x;
    const int node0 = b << BIN_SHIFT;
    const int t = threadIdx.x;
    if (t < 128) h[t] = 0;
    __syncthreads();
    const int e0 = cs[b], e1 = cs[b + 1];
    for (int e = e0 + t; e < e1; e += 256)
        atomicAdd(&h[ebuf[e] & 127], 1);
    __syncthreads();
    if (t < 128) fs[t] = h[t];
    __syncthreads();
    for (int off = 1; off < 128; off <<= 1) {
        int v = 0;
        if (t < 128 && t >= off) v = fs[t - off];
        __syncthreads();
        if (t < 128) fs[t] += v;  // inclusive scan
        __syncthreads();
    }
    if (t < 128) {
        int node = node0 + t;
        if (node < n) {
            int cnt = h[t];
            degi[node] = cnt;
            rowptr[node] = e0 + fs[t] - cnt;
            dinv[node] = rsqrtf((float)cnt + 1.0f);
        }
        cur[t] = 0;
    }
    __syncthreads();
    for (int e = e0 + t; e < e1; e += 256) {
        int p = ebuf[e];
        int li = p & 127;
        int loc = atomicAdd(&cur[li], 1);
        col[e0 + (fs[li] - h[li]) + loc] = p >> BIN_SHIFT;
    }
}

// ---------------- MFMA bf16 GEMM (layer1): Y(bf16) = dinv[row] * (X @ W) ----------------
template <typename InT, int K, int M, int WM, int WN>
__global__ __launch_bounds__(256) void gemm_mfma_kernel(const InT* __restrict__ X,
                                                        const unsigned short* __restrict__ Wfrag,
                                                        const float* __restrict__ dinv,
                                                        unsigned short* __restrict__ Y,
                                                        int n, int ntiles) {
    constexpr int BM = 64;
    constexpr int WR = BM / WM;
    constexpr int WC = M / WN;
    constexpr int RF = WR / 16;
    constexpr int CF = WC / 16;
    constexpr int KS = K / 32;
    constexpr int ROWB = K * 2;
    constexpr int UPR = ROWB / 16;

    __shared__ char Xs[BM * ROWB];

    const int tid = threadIdx.x;
    const int lane = tid & 63;
    const int wid = tid >> 6;
    const int wrow = wid / WN;
    const int wcol = wid % WN;
    const int l15 = lane & 15;
    const int lhi = lane >> 4;

    s16x8 bfrag[CF][KS];
#pragma unroll
    for (int cf = 0; cf < CF; ++cf)
#pragma unroll
        for (int ks = 0; ks < KS; ++ks)
            bfrag[cf][ks] = *(const s16x8*)(Wfrag +
                (size_t)(((wcol * CF + cf) * KS + ks) * 64 + lane) * 8);

    for (int tile = blockIdx.x; tile < ntiles; tile += gridDim.x) {
        const int row0 = tile * BM;
        __syncthreads();
#pragma unroll
        for (int i = 0; i < (BM * UPR) / 256; ++i) {
            int g = i * 256 + tid;
            int r = g / UPR, u = g % UPR;
            int grow = row0 + r;
            int4 val = make_int4(0, 0, 0, 0);
            if (grow < n) {
                if constexpr (sizeof(InT) == 4) {
                    const float* src = (const float*)X + (size_t)grow * K + u * 8;
                    float4 f0 = *(const float4*)src;
                    float4 f1 = *(const float4*)(src + 4);
                    val.x = (int)(f2bf(f0.x) | ((unsigned int)f2bf(f0.y) << 16));
                    val.y = (int)(f2bf(f0.z) | ((unsigned int)f2bf(f0.w) << 16));
                    val.z = (int)(f2bf(f1.x) | ((unsigned int)f2bf(f1.y) << 16));
                    val.w = (int)(f2bf(f1.z) | ((unsigned int)f2bf(f1.w) << 16));
                } else {
                    val = *(const int4*)((const unsigned short*)X + (size_t)grow * K + u * 8);
                }
            }
            *(int4*)(Xs + r * ROWB + ((u ^ (r & 7)) * 16)) = val;
        }
        __syncthreads();

        f32x4 acc[RF][CF];
#pragma unroll
        for (int rf = 0; rf < RF; ++rf)
#pragma unroll
            for (int cf = 0; cf < CF; ++cf) acc[rf][cf] = (f32x4)(0.0f);
#pragma unroll
        for (int ks = 0; ks < KS; ++ks) {
            s16x8 afrag[RF];
#pragma unroll
            for (int rf = 0; rf < RF; ++rf) {
                int r = wrow * WR + rf * 16 + l15;
                int u = ks * 4 + lhi;
                afrag[rf] = *(const s16x8*)(Xs + r * ROWB + ((u ^ (r & 7)) * 16));
            }
#pragma unroll
            for (int rf = 0; rf < RF; ++rf)
#pragma unroll
                for (int cf = 0; cf < CF; ++cf)
                    acc[rf][cf] = __builtin_amdgcn_mfma_f32_16x16x32_bf16(
                        afrag[rf], bfrag[cf][ks], acc[rf][cf], 0, 0, 0);
        }

#pragma unroll
        for (int rf = 0; rf < RF; ++rf) {
#pragma unroll
            for (int reg = 0; reg < 4; ++reg) {
                int grow = row0 + wrow * WR + rf * 16 + lhi * 4 + reg;
                if (grow < n) {
                    float dv = dinv[grow];
#pragma unroll
                    for (int cf = 0; cf < CF; ++cf) {
                        int colg = wcol * WC + cf * 16 + l15;
                        Y[(size_t)grow * M + colg] = f2bf(acc[rf][cf][reg] * dv);
                    }
                }
            }
        }
    }
}

// ======== FUSED: h=relu(dinv*agg(Hs1)+b1) -> LDS bf16 tile -> Hs2=bf16(dinv*(h@W2)) ========
__global__ __launch_bounds__(256) void gather_gemm_kernel(
    const unsigned short* __restrict__ Hs1, const int* __restrict__ rowptr,
    const int* __restrict__ degi, const int* __restrict__ col,
    const float* __restrict__ dinv, const float* __restrict__ b1,
    const unsigned short* __restrict__ W2f, unsigned short* __restrict__ Hs2, int n) {
    __shared__ char h_tile[16 * 256];

    const int tid = threadIdx.x;
    const int lane = tid & 63;
    const int wv = tid >> 6;
    const int sub = lane & 15;
    const int grp = lane >> 4;
    const int node0 = blockIdx.x * 16;
    const int local = wv * 4 + grp;
    const int node = node0 + local;
    const int foff = sub * 8;

    s16x8 bfrag[4];
#pragma unroll
    for (int ks = 0; ks < 4; ++ks)
        bfrag[ks] = *(const s16x8*)(W2f + (size_t)((wv * 4 + ks) * 64 + lane) * 8);

    if (node < n) {
        const int start = rowptr[node];
        const int cnt = degi[node];
        const float dvn = dinv[node];
        float acc[8];
        {
            int4 v = *(const int4*)(Hs1 + (size_t)node * HIDN + foff);
#pragma unroll
            for (int q = 0; q < 4; ++q) {
                unsigned int w = ((const unsigned int*)&v)[q];
                acc[2 * q] = bflo(w);
                acc[2 * q + 1] = bfhi(w);
            }
        }
        int m0 = imin(cnt, 16);
        int sv = (sub < m0) ? col[start + sub] : 0;
        for (int base = 0; base < cnt; base += 16) {
            int m = imin(cnt - base, 16);
            int svn = 0;
            int nb = base + 16;
            if (nb < cnt) {
                int mn = imin(cnt - nb, 16);
                svn = (sub < mn) ? col[start + nb + sub] : 0;
            }
            int k = 0;
            for (; k + 8 <= m; k += 8) {
                int4 a[8];
#pragma unroll
                for (int j = 0; j < 8; ++j) {
                    int s = __shfl(sv, k + j, 16);
                    a[j] = *(const int4*)(Hs1 + (size_t)s * HIDN + foff);
                }
#pragma unroll
                for (int j = 0; j < 8; ++j)
#pragma unroll
                    for (int q = 0; q < 4; ++q) {
                        unsigned int w = ((const unsigned int*)&a[j])[q];
                        acc[2 * q] += bflo(w);
                        acc[2 * q + 1] += bfhi(w);
                    }
            }
            for (; k + 2 <= m; k += 2) {
                int s0 = __shfl(sv, k, 16);
                int s1 = __shfl(sv, k + 1, 16);
                int4 a0 = *(const int4*)(Hs1 + (size_t)s0 * HIDN + foff);
                int4 a1 = *(const int4*)(Hs1 + (size_t)s1 * HIDN + foff);
#pragma unroll
                for (int q = 0; q < 4; ++q) {
                    unsigned int w0 = ((const unsigned int*)&a0)[q];
                    unsigned int w1 = ((const unsigned int*)&a1)[q];
                    acc[2 * q] += bflo(w0);
                    acc[2 * q + 1] += bfhi(w0);
                    acc[2 * q] += bflo(w1);
                    acc[2 * q + 1] += bfhi(w1);
                }
            }
            for (; k < m; ++k) {
                int s = __shfl(sv, k, 16);
                int4 a = *(const int4*)(Hs1 + (size_t)s * HIDN + foff);
#pragma unroll
                for (int q = 0; q < 4; ++q) {
                    unsigned int w = ((const unsigned int*)&a)[q];
                    acc[2 * q] += bflo(w);
                    acc[2 * q + 1] += bfhi(w);
                }
            }
            sv = svn;
        }
        float4 bv0 = *(const float4*)(b1 + foff);
        float4 bv1 = *(const float4*)(b1 + foff + 4);
        float o[8];
        o[0] = fmaxf(dvn * acc[0] + bv0.x, 0.f);
        o[1] = fmaxf(dvn * acc[1] + bv0.y, 0.f);
        o[2] = fmaxf(dvn * acc[2] + bv0.z, 0.f);
        o[3] = fmaxf(dvn * acc[3] + bv0.w, 0.f);
        o[4] = fmaxf(dvn * acc[4] + bv1.x, 0.f);
        o[5] = fmaxf(dvn * acc[5] + bv1.y, 0.f);
        o[6] = fmaxf(dvn * acc[6] + bv1.z, 0.f);
        o[7] = fmaxf(dvn * acc[7] + bv1.w, 0.f);
        int4 p;
        ((unsigned int*)&p)[0] = f2bf(o[0]) | ((unsigned int)f2bf(o[1]) << 16);
        ((unsigned int*)&p)[1] = f2bf(o[2]) | ((unsigned int)f2bf(o[3]) << 16);
        ((unsigned int*)&p)[2] = f2bf(o[4]) | ((unsigned int)f2bf(o[5]) << 16);
        ((unsigned int*)&p)[3] = f2bf(o[6]) | ((unsigned int)f2bf(o[7]) << 16);
        *(int4*)(h_tile + local * 256 + ((sub ^ (local & 7)) * 16)) = p;
    }
    __syncthreads();

    f32x4 acc2 = (f32x4)(0.0f);
#pragma unroll
    for (int ks = 0; ks < 4; ++ks) {
        int r = sub;
        int u = ks * 4 + grp;
        s16x8 af = *(const s16x8*)(h_tile + r * 256 + ((u ^ (r & 7)) * 16));
        acc2 = __builtin_amdgcn_mfma_f32_16x16x32_bf16(af, bfrag[ks], acc2, 0, 0, 0);
    }
#pragma unroll
    for (int reg = 0; reg < 4; ++reg) {
        int row = grp * 4 + reg;
        int nd = node0 + row;
        if (nd < n)
            Hs2[(size_t)nd * EMBD + wv * 16 + sub] = f2bf(acc2[reg] * dinv[nd]);
    }
}

// ======== FUSED final: emb = dinv*agg(Hs2)+b2 (f32) ; MFMA logits ; log_softmax ========
__global__ __launch_bounds__(256) void gather2_lsm_kernel(
    const unsigned short* __restrict__ Hs, const int* __restrict__ rowptr,
    const int* __restrict__ degi, const int* __restrict__ col,
    const float* __restrict__ dinv, const float* __restrict__ b2,
    const unsigned short* __restrict__ Wlf, const float* __restrict__ bl,
    float* __restrict__ emb, float* __restrict__ lsm, int n) {
    __shared__ char h_tile[32 * 128];
    __shared__ float lg[32][49];
    __shared__ float bls[OUTC];

    const int tid = threadIdx.x;
    if (tid < OUTC) bls[tid] = bl[tid];
    const int lane = tid & 63;
    const int wv = tid >> 6;
    const int sub = lane & 7;
    const int grp = lane >> 3;
    const int local = wv * 8 + grp;
    const int node0 = blockIdx.x * 32;
    const int node = node0 + local;
    const int foff = sub * 8;

    if (node < n) {
        const int start = rowptr[node];
        const int cnt = degi[node];
        const float dvn = dinv[node];
        float acc[8];
        {
            int4 v = *(const int4*)(Hs + (size_t)node * EMBD + foff);
#pragma unroll
            for (int q = 0; q < 4; ++q) {
                unsigned int w = ((const unsigned int*)&v)[q];
                acc[2 * q] = bflo(w);
                acc[2 * q + 1] = bfhi(w);
            }
        }
        int m0 = imin(cnt, 8);
        int sv = (sub < m0) ? col[start + sub] : 0;
        for (int base = 0; base < cnt; base += 8) {
            int m = imin(cnt - base, 8);
            int svn = 0;
            int nb = base + 8;
            if (nb < cnt) {
                int mn = imin(cnt - nb, 8);
                svn = (sub < mn) ? col[start + nb + sub] : 0;
            }
            int k = 0;
            for (; k + 8 <= m; k += 8) {
                int4 a[8];
#pragma unroll
                for (int j = 0; j < 8; ++j) {
                    int s = __shfl(sv, k + j, 8);
                    a[j] = *(const int4*)(Hs + (size_t)s * EMBD + foff);
                }
#pragma unroll
                for (int j = 0; j < 8; ++j)
#pragma unroll
                    for (int q = 0; q < 4; ++q) {
                        unsigned int w = ((const unsigned int*)&a[j])[q];
                        acc[2 * q] += bflo(w);
                        acc[2 * q + 1] += bfhi(w);
                    }
            }
            for (; k < m; ++k) {
                int s = __shfl(sv, k, 8);
                int4 a = *(const int4*)(Hs + (size_t)s * EMBD + foff);
#pragma unroll
                for (int q = 0; q < 4; ++q) {
                    unsigned int w = ((const unsigned int*)&a)[q];
                    acc[2 * q] += bflo(w);
                    acc[2 * q + 1] += bfhi(w);
                }
            }
            sv = svn;
        }

        float4 bv0 = *(const float4*)(b2 + foff);
        float4 bv1 = *(const float4*)(b2 + foff + 4);
        float o[8];
        o[0] = dvn * acc[0] + bv0.x; o[1] = dvn * acc[1] + bv0.y;
        o[2] = dvn * acc[2] + bv0.z; o[3] = dvn * acc[3] + bv0.w;
        o[4] = dvn * acc[4] + bv1.x; o[5] = dvn * acc[5] + bv1.y;
        o[6] = dvn * acc[6] + bv1.z; o[7] = dvn * acc[7] + bv1.w;
        *(float4*)(emb + (size_t)node * EMBD + foff) = make_float4(o[0], o[1], o[2], o[3]);
        *(float4*)(emb + (size_t)node * EMBD + foff + 4) = make_float4(o[4], o[5], o[6], o[7]);
        int4 p;
        ((unsigned int*)&p)[0] = f2bf(o[0]) | ((unsigned int)f2bf(o[1]) << 16);
        ((unsigned int*)&p)[1] = f2bf(o[2]) | ((unsigned int)f2bf(o[3]) << 16);
        ((unsigned int*)&p)[2] = f2bf(o[4]) | ((unsigned int)f2bf(o[5]) << 16);
        ((unsigned int*)&p)[3] = f2bf(o[6]) | ((unsigned int)f2bf(o[7]) << 16);
        *(int4*)(h_tile + local * 128 + ((sub ^ (local & 7)) * 16)) = p;
    }
    __syncthreads();

    const int l15 = lane & 15;
    const int lhi = lane >> 4;
#pragma unroll
    for (int it = 0; it < 2; ++it) {
        int t = wv + it * 4;
        if (t < 6) {
            int rt = t & 1, ct = t >> 1;
            f32x4 accl = (f32x4)(0.0f);
#pragma unroll
            for (int ks = 0; ks < 2; ++ks) {
                int r = rt * 16 + l15;
                int u = ks * 4 + lhi;
                s16x8 af = *(const s16x8*)(h_tile + r * 128 + ((u ^ (r & 7)) * 16));
                s16x8 bf = *(const s16x8*)(Wlf + (size_t)((ct * 2 + ks) * 64 + lane) * 8);
                accl = __builtin_amdgcn_mfma_f32_16x16x32_bf16(af, bf, accl, 0, 0, 0);
            }
#pragma unroll
            for (int reg = 0; reg < 4; ++reg)
                lg[rt * 16 + lhi * 4 + reg][ct * 16 + l15] = accl[reg];
        }
    }
    __syncthreads();

    if (tid < 32) {
        int nd = node0 + tid;
        if (nd < n) {
            float logit[OUTC];
            float mx = -INFINITY;
#pragma unroll
            for (int c = 0; c < OUTC; ++c) {
                float v = lg[tid][c] + bls[c];
                logit[c] = v;
                mx = fmaxf(mx, v);
            }
            float ss = 0.0f;
#pragma unroll
            for (int c = 0; c < OUTC; ++c) ss += expf(logit[c] - mx);
            float lse = mx + logf(ss);
            float* op = lsm + (size_t)nd * OUTC;
#pragma unroll
            for (int c = 0; c < OUTC; ++c) op[c] = logit[c] - lse;
        }
    }
}

extern "C" void kernel_launch(void* const* d_in, const int* in_sizes, int n_in,
                              void* d_out, int out_size, void* d_ws, size_t ws_size,
                              hipStream_t stream) {
    const float* x  = (const float*)d_in[0];
    const int*   ei = (const int*)d_in[1];
    const float* W1 = (const float*)d_in[2];
    const float* b1 = (const float*)d_in[3];
    const float* W2 = (const float*)d_in[4];
    const float* b2 = (const float*)d_in[5];
    const float* Wl = (const float*)d_in[6];
    const float* bl = (const float*)d_in[7];

    const int N = in_sizes[0] / F_IN;
    const int E = in_sizes[1] / 2;
    const int* srcp = ei;
    const int* dstp = ei + E;

    float* out = (float*)d_out;
    float* lsm = out;                        // N x 40
    float* emb = out + (size_t)N * OUTC;     // N x 64

    float* ws    = (float*)d_ws;
    float* dinv  = ws;                              // N
    int*   degi  = (int*)(ws + N);                  // N
    int*   rowptr= degi + N;                        // N
    int*   cs    = rowptr + N;                      // NBINS+1 (pad 1056)
    int*   bintot= cs + 1056;                       // NBINS
    int*   bc    = bintot + NBINS;                  // CSR_BLKS*NBINS (block-major)
    unsigned short* W1f = (unsigned short*)(bc + CSR_BLKS * NBINS);  // 16384
    unsigned short* W2f = W1f + 16384;                               // 8192
    unsigned short* Wlf = W2f + 8192;                                // 3072
    int*   col   = (int*)(Wlf + 3072);              // E
    int*   ebuf  = col + E;                         // E (packed (src<<7)|dst7)
    unsigned short* Hs1 = (unsigned short*)(ebuf + E);     // N x 128 bf16
    unsigned short* Hs2 = Hs1 + (size_t)N * HIDN;          // N x 64 bf16

    const int B = 256;
    const int ntiles = (N + 63) / 64;

    // --- weight fragments (tiny, once) ---
    prep_frags_kernel<<<14, B, 0, stream>>>(W1, W2, Wl, W1f, W2f, Wlf);

    // --- CSR build (two-level counting sort, LDS atomics only) ---
    coarse_hist_kernel<<<CSR_BLKS, B, 0, stream>>>(dstp, bc, E);
    bin_prefix_kernel<<<NBINS / 64, 64, 0, stream>>>(bc, bintot);
    bin_scan_kernel<<<1, 1024, 0, stream>>>(bintot, cs);
    bin_scatter_kernel<<<CSR_BLKS, B, 0, stream>>>(srcp, dstp, bc, cs, ebuf, E);
    fine_build_kernel<<<(N + 127) / 128, B, 0, stream>>>(ebuf, cs, degi, rowptr, dinv, col, N);

    // --- layer 1 GEMM: Hs1 = bf16(dinv .* (x @ W1)) ---
    gemm_mfma_kernel<float, F_IN, HIDN, 2, 2><<<ntiles, B, 0, stream>>>(x, W1f, dinv, Hs1, N, ntiles);

    // --- fused: gather layer1 + ReLU + GEMM2 -> Hs2 = bf16(dinv .* (h @ W2)) ---
    gather_gemm_kernel<<<(N + 15) / 16, B, 0, stream>>>(
        Hs1, rowptr, degi, col, dinv, b1, W2f, Hs2, N);

    // --- fused: gather layer2 -> emb + MFMA logits + log_softmax ---
    gather2_lsm_kernel<<<(N + 31) / 32, B, 0, stream>>>(
        Hs2, rowptr, degi, col, dinv, b2, Wlf, bl, emb, lsm, N);
}